// Round 5
// baseline (730.416 us; speedup 1.0000x reference)
//
#include <hip/hip_runtime.h>

#define W 512
#define NPX (512*512)
#define NCH 48
#define NBATCH 16

// reflect-101 index mapping into [0,511]; valid for i in [-511, 1022]
__device__ __forceinline__ int refl(int i) {
    int a = i < 0 ? -i : i;
    int b = 1022 - a;
    return a < b ? a : b;
}
__device__ __forceinline__ unsigned encf(float f) {
    unsigned u = __float_as_uint(f);
    return (u & 0x80000000u) ? ~u : (u | 0x80000000u);
}
__device__ __forceinline__ float decf(unsigned e) {
    unsigned u = (e & 0x80000000u) ? (e & 0x7FFFFFFFu) : ~e;
    return __uint_as_float(u);
}
__device__ __forceinline__ unsigned long long enc64(double d) {
    unsigned long long u = (unsigned long long)__double_as_longlong(d);
    return (u & 0x8000000000000000ULL) ? ~u : (u | 0x8000000000000000ULL);
}
__device__ __forceinline__ double dec64(unsigned long long e) {
    unsigned long long u = (e & 0x8000000000000000ULL) ? (e & 0x7FFFFFFFFFFFFFFFULL) : ~e;
    return __longlong_as_double((long long)u);
}

__global__ void initK(unsigned* minenc, unsigned* maxenc, unsigned long long* rmaxenc,
                      unsigned* rowact) {
    int t = threadIdx.x;
    if (t < NCH) { minenc[t] = 0xFFFFFFFFu; maxenc[t] = 0u; rmaxenc[t] = 0ULL; }
    for (int i = t; i < NCH*16; i += 1024) rowact[i] = 0u;
}

// weights: gw[o*288 + k] = g[k] for k in [0, 2r], zero elsewhere (k < 288)
__global__ void gaussK(float* gw) {
    int o = blockIdx.x;
    const int rr[6] = {4, 8, 17, 34, 67, 134};
    int r = rr[o];
    float sigma = 1.4f * (float)(1 << o);
    int t = threadIdx.x;   // 512
    int n = 2*r + 1;
    float wv = 0.f;
    if (t < n) { float ft = (float)(t - r) / sigma; wv = expf(-0.5f * ft * ft); }
    __shared__ float red[512];
    red[t] = wv; __syncthreads();
    for (int s = 256; s > 0; s >>= 1) { if (t < s) red[t] += red[t + s]; __syncthreads(); }
    float sum = red[0];
    float* g = gw + o*288;
    if (t < 288) g[t] = (t < n) ? wv / sum : 0.f;
}

__global__ void minmaxK(const float4* __restrict__ x4, unsigned* minenc, unsigned* maxenc) {
    int ch = blockIdx.y, chunk = blockIdx.x, t = threadIdx.x;
    size_t base = (size_t)ch*(NPX/4) + (size_t)chunk*8192;
    float mn = 3.4e38f, mx = -3.4e38f;
    for (int i = t; i < 8192; i += 256) {
        float4 v = x4[base + i];
        mn = fminf(mn, fminf(fminf(v.x, v.y), fminf(v.z, v.w)));
        mx = fmaxf(mx, fmaxf(fmaxf(v.x, v.y), fmaxf(v.z, v.w)));
    }
    for (int o = 32; o; o >>= 1) { mn = fminf(mn, __shfl_down(mn, o)); mx = fmaxf(mx, __shfl_down(mx, o)); }
    __shared__ float smn[4], smx[4];
    if ((t & 63) == 0) { smn[t >> 6] = mn; smx[t >> 6] = mx; }
    __syncthreads();
    if (t == 0) {
        for (int i = 1; i < 4; i++) { mn = fminf(mn, smn[i]); mx = fmaxf(mx, smx[i]); }
        atomicMin(&minenc[ch], encf(mn));
        atomicMax(&maxenc[ch], encf(mx));
    }
}

__global__ void scaleK(const unsigned* minenc, const unsigned* maxenc, double* gsd) {
    int t = threadIdx.x;
    if (t >= NCH) return;
    double mn = (double)decf(minenc[t]), mx = (double)decf(maxenc[t]);
    gsd[t] = 255.0 / (mx - mn + 1e-12);
}

// Harris R (fp64 direct, no P maps) + Laplacian base. 32x32 tile/block, 5.2KB LDS.
// Box positions {ya,yb}x{xa,xb} always occupy window slots {1,2}x{1,2} of the
// 4x4 window at base (gy?gy-2:-1, gx?gx-2:-1) -> border cases vanish.
__global__ __launch_bounds__(256) void lapRK(const float* __restrict__ x, const double* __restrict__ gsd,
                      float* __restrict__ lap, double* __restrict__ Rb,
                      unsigned long long* __restrict__ rmaxenc) {
    __shared__ float in[36*36];
    int ch = blockIdx.z;
    int px0 = blockIdx.x * 32, py0 = blockIdx.y * 32;
    const float* s = x + (size_t)ch*NPX;
    int t = threadIdx.x;
    for (int i = t; i < 36*36; i += 256) {
        int yy = i / 36, xx = i - yy*36;
        in[i] = s[(size_t)refl(py0 - 2 + yy)*W + refl(px0 - 2 + xx)];
    }
    __syncthreads();
    double sd = gsd[ch], s2 = sd*sd;
    int tx = t & 31, ty0 = (t >> 5) * 4;
    int gx = px0 + tx;
    int cb = gx ? tx : 1;               // local col of window base
    double m = -1e308;
    #pragma unroll
    for (int q = 0; q < 4; q++) {
        int ly = ty0 + q;
        int gy = py0 + ly;
        int rb = gy ? ly : 1;           // local row of window base
        double w[4][4];
        #pragma unroll
        for (int j = 0; j < 4; j++) {
            const float* rp = &in[(rb + j)*36 + cb];
            w[j][0] = (double)rp[0]; w[j][1] = (double)rp[1];
            w[j][2] = (double)rp[2]; w[j][3] = (double)rp[3];
        }
        double cs1[4], cs2[4], rs[4][2];
        #pragma unroll
        for (int c2 = 0; c2 < 4; c2++) {
            cs1[c2] = w[0][c2] + 2.0*w[1][c2] + w[2][c2];
            cs2[c2] = w[1][c2] + 2.0*w[2][c2] + w[3][c2];
        }
        #pragma unroll
        for (int j = 0; j < 4; j++) {
            rs[j][0] = w[j][0] + 2.0*w[j][1] + w[j][2];
            rs[j][1] = w[j][1] + 2.0*w[j][2] + w[j][3];
        }
        double Sxx = 0, Syy = 0, Sxy = 0;
        {
            double ix, iy;
            ix = cs1[2]-cs1[0]; iy = rs[2][0]-rs[0][0]; Sxx += ix*ix; Syy += iy*iy; Sxy += ix*iy;
            ix = cs1[3]-cs1[1]; iy = rs[2][1]-rs[0][1]; Sxx += ix*ix; Syy += iy*iy; Sxy += ix*iy;
            ix = cs2[2]-cs2[0]; iy = rs[3][0]-rs[1][0]; Sxx += ix*ix; Syy += iy*iy; Sxy += ix*iy;
            ix = cs2[3]-cs2[1]; iy = rs[3][1]-rs[1][1]; Sxx += ix*ix; Syy += iy*iy; Sxy += ix*iy;
        }
        Sxx *= s2; Syy *= s2; Sxy *= s2;
        double tr = Sxx + Syy;
        double R = Sxx*Syy - Sxy*Sxy - 0.04*tr*tr;
        Rb[(size_t)ch*NPX + (size_t)gy*W + gx] = R;
        const float* c = &in[(ly+2)*36 + (tx+2)];
        double l = 2.0*((double)c[-37] + (double)c[-35] + (double)c[35] + (double)c[37]) - 8.0*(double)c[0];
        lap[(size_t)ch*NPX + (size_t)gy*W + gx] = (float)(sd * l);
        m = fmax(m, R);
    }
    for (int o = 32; o; o >>= 1) m = fmax(m, __shfl_down(m, o));
    __shared__ double sred[4];
    if ((t & 63) == 0) sred[t >> 6] = m;
    __syncthreads();
    if (t == 0) {
        for (int i = 1; i < 4; i++) m = fmax(m, sred[i]);
        atomicMax(&rmaxenc[ch], enc64(m));
    }
}

// fused threshold + 3x3 dilate; also builds per-channel row-activity bitmap
__global__ __launch_bounds__(256) void maskTK(const double* __restrict__ Rb,
                                              const unsigned long long* __restrict__ rmaxenc,
                                              unsigned char* __restrict__ maskb,
                                              unsigned* __restrict__ rowact) {
    __shared__ int bt[34*34];
    __shared__ unsigned rw;
    int ch = blockIdx.z;
    int px0 = blockIdx.x*32, py0 = blockIdx.y*32;
    double thr = 0.01 * dec64(rmaxenc[ch]);
    const double* R = Rb + (size_t)ch*NPX;
    int t = threadIdx.x;
    if (t == 0) rw = 0u;
    for (int i = t; i < 34*34; i += 256) {
        int yy = i / 34, xx = i - yy*34;
        int gy = py0 - 1 + yy, gx = px0 - 1 + xx;
        int v = 0;
        if ((unsigned)gy < 512u && (unsigned)gx < 512u) v = (R[(size_t)gy*W + gx] > thr) ? 1 : 0;
        bt[i] = v;
    }
    __syncthreads();
    int tx = t & 31, ty0 = (t >> 5) * 4;
    #pragma unroll
    for (int q = 0; q < 4; q++) {
        int ly = ty0 + q;
        int c = (ly+1)*34 + tx + 1;
        int v = bt[c-35] | bt[c-34] | bt[c-33] | bt[c-1] | bt[c] | bt[c+1] | bt[c+33] | bt[c+34] | bt[c+35];
        maskb[(size_t)ch*NPX + (size_t)(py0+ly)*W + px0 + tx] = (unsigned char)v;
        unsigned long long bal = __ballot(v != 0);
        int lane = t & 63;
        if (lane == 0 && (unsigned)bal) atomicOr(&rw, 1u << (ty0 + q));
        if (lane == 32 && (unsigned)(bal >> 32)) atomicOr(&rw, 1u << (ty0 + q));
    }
    __syncthreads();
    if (t == 0 && rw) atomicOr(&rowact[ch*16 + (py0 >> 5)], rw);
}

// horizontal blur: 8 rows/block, 16 px/thread, 16-tap chunks; row-activity early-exit.
__global__ __launch_bounds__(256) void rowblurK(const float* __restrict__ src, float* __restrict__ dst,
                                                const float* __restrict__ gwo, int r, int nc2,
                                                const unsigned* __restrict__ rowact) {
    int ch = blockIdx.y;
    int row0 = blockIdx.x * 8;
    int t = threadIdx.x;
    // early exit: no mask row in [row0-r-7, row0+7+r]  (-7 slop covers zero-weight taps)
    {
        int lo = row0 - r - 7; if (lo < 0) lo = 0;
        int hi = row0 + 7 + r; if (hi > 511) hi = 511;
        int w0 = lo >> 5, w1 = hi >> 5;
        int lane = t & 63;
        unsigned any = 0;
        if (lane <= w1 - w0) {
            int wi = w0 + lane;
            unsigned word = rowact[ch*16 + wi];
            int b0 = wi*32;
            int lo2 = lo > b0 ? lo - b0 : 0;
            int hi2 = hi < b0 + 31 ? hi - b0 : 31;
            unsigned mlo = ~0u << lo2;
            unsigned mhi = (hi2 == 31) ? ~0u : ((1u << (hi2 + 1)) - 1u);
            any = word & mlo & mhi;
        }
        if (!__any((int)(any != 0))) return;
    }
    __shared__ float ES[8][16][49];
    __shared__ float wl[272];
    int lr = t >> 5, xi = t & 31;
    for (int i = t; i < 272; i += 256) wl[i] = gwo[i];
    const float* s = src + (size_t)ch*NPX + (size_t)(row0 + lr)*W;
    int n = W + 2*r;
    for (int j = xi; j < 784; j += 32) {
        float v = (j < n) ? s[refl(j - r)] : 0.f;
        ES[lr][j & 15][j >> 4] = v;
    }
    __syncthreads();
    float a[16];
    #pragma unroll
    for (int m = 0; m < 16; m++) a[m] = 0.f;
    for (int cc = 0; cc < nc2; ++cc) {
        float wv[16], f[31];
        #pragma unroll
        for (int i = 0; i < 16; i++) wv[i] = wl[16*cc + i];
        #pragma unroll
        for (int j = 0; j < 31; j++) f[j] = ES[lr][j & 15][xi + cc + (j >> 4)];
        #pragma unroll
        for (int m = 0; m < 16; m++) {
            #pragma unroll
            for (int i = 0; i < 16; i++) a[m] = fmaf(wv[i], f[m + i], a[m]);
        }
    }
    float4* d4 = (float4*)(dst + (size_t)ch*NPX + (size_t)(row0 + lr)*W + xi*16);
    d4[0] = make_float4(a[0],  a[1],  a[2],  a[3]);
    d4[1] = make_float4(a[4],  a[5],  a[6],  a[7]);
    d4[2] = make_float4(a[8],  a[9],  a[10], a[11]);
    d4[3] = make_float4(a[12], a[13], a[14], a[15]);
}

// vertical blur + mask + sigma*|.| + channel-max + octave-max.
// 256-row band x 32 cols; thread = 4 cols x 8 rows; CHUNK=8 taps with rolling
// f[15] register window (7 reused + 8 new LDS b128 per chunk -> VALU-bound).
// Mask-first per-channel skip of staging+compute; skip output RMW if block idle.
__global__ __launch_bounds__(256) void colblurK(const float* __restrict__ T, const unsigned char* __restrict__ maskb,
                                                float* __restrict__ out, const float* __restrict__ gwo,
                                                int r, int nchunk, int rowsAlloc, float sigma, int write0) {
    extern __shared__ __align__(16) float tile[];   // [rowsAlloc][36] + wl[288]
    float* wl = tile + rowsAlloc*36;
    int x0 = blockIdx.x * 32;
    int band0 = blockIdx.y * 256;
    int b = blockIdx.z;
    int t = threadIdx.x;
    int cg = t & 7, rg = t >> 3;
    int j0 = rg * 8;
    int rowsData = 256 + 2*r;
    for (int i = t; i < 288; i += 256) wl[i] = gwo[i];
    float4 vm[8];
    #pragma unroll
    for (int m = 0; m < 8; m++) vm[m] = make_float4(0.f, 0.f, 0.f, 0.f);
    int anyAct = 0;
    for (int c = 0; c < 3; ++c) {
        int ch = b*3 + c;
        const unsigned char* mp = maskb + (size_t)ch*NPX + (size_t)(band0 + j0)*W + x0 + 4*cg;
        unsigned mk = 0;
        #pragma unroll
        for (int m = 0; m < 8; m++) {
            uchar4 u = *(const uchar4*)(mp + (size_t)m*W);
            mk |= ((u.x ? 1u : 0u) | (u.y ? 2u : 0u) | (u.z ? 4u : 0u) | (u.w ? 8u : 0u)) << (4*m);
        }
        int act = __syncthreads_or((int)(mk != 0));
        if (!act) continue;
        anyAct = 1;
        const float* src = T + (size_t)ch*NPX;
        for (int ly = rg; ly < rowsAlloc; ly += 32) {
            float4 v = make_float4(0.f, 0.f, 0.f, 0.f);
            if (ly < rowsData) v = *(const float4*)(src + (size_t)refl(band0 - r + ly)*W + x0 + 4*cg);
            *(float4*)(tile + ly*36 + 4*cg) = v;
        }
        __syncthreads();
        if (__any((int)(mk != 0))) {
            float4 a[8];
            #pragma unroll
            for (int m = 0; m < 8; m++) a[m] = make_float4(0.f, 0.f, 0.f, 0.f);
            const float* tb = tile + j0*36 + 4*cg;
            float4 f[15];
            #pragma unroll
            for (int j = 0; j < 15; j++) f[j] = *(const float4*)(tb + j*36);
            for (int cc = 0; cc < nchunk; ++cc) {
                if (cc) {
                    #pragma unroll
                    for (int j = 0; j < 7; j++) f[j] = f[j+8];
                    #pragma unroll
                    for (int j = 7; j < 15; j++) f[j] = *(const float4*)(tb + (8*cc + j)*36);
                }
                float wv[8];
                #pragma unroll
                for (int qq = 0; qq < 2; qq++) {
                    float4 w4 = *(const float4*)(wl + 8*cc + 4*qq);
                    wv[4*qq] = w4.x; wv[4*qq+1] = w4.y; wv[4*qq+2] = w4.z; wv[4*qq+3] = w4.w;
                }
                #pragma unroll
                for (int m = 0; m < 8; m++) {
                    #pragma unroll
                    for (int i = 0; i < 8; i++) {
                        a[m].x = fmaf(wv[i], f[m+i].x, a[m].x);
                        a[m].y = fmaf(wv[i], f[m+i].y, a[m].y);
                        a[m].z = fmaf(wv[i], f[m+i].z, a[m].z);
                        a[m].w = fmaf(wv[i], f[m+i].w, a[m].w);
                    }
                }
            }
            #pragma unroll
            for (int m = 0; m < 8; m++) {
                if (mk & (1u << (4*m+0))) vm[m].x = fmaxf(vm[m].x, sigma*fabsf(a[m].x));
                if (mk & (1u << (4*m+1))) vm[m].y = fmaxf(vm[m].y, sigma*fabsf(a[m].y));
                if (mk & (1u << (4*m+2))) vm[m].z = fmaxf(vm[m].z, sigma*fabsf(a[m].z));
                if (mk & (1u << (4*m+3))) vm[m].w = fmaxf(vm[m].w, sigma*fabsf(a[m].w));
            }
        }
    }
    if (!anyAct && !write0) return;
    float* ob = out + (size_t)b*NPX + (size_t)(band0 + j0)*W + x0 + 4*cg;
    #pragma unroll
    for (int m = 0; m < 8; m++) {
        float4 v = vm[m];
        if (!write0) {
            float4 cur = *(const float4*)(ob + (size_t)m*W);
            v.x = fmaxf(v.x, cur.x); v.y = fmaxf(v.y, cur.y);
            v.z = fmaxf(v.z, cur.z); v.w = fmaxf(v.w, cur.w);
        }
        *(float4*)(ob + (size_t)m*W) = v;
    }
}

extern "C" void kernel_launch(void* const* d_in, const int* in_sizes, int n_in,
                              void* d_out, int out_size, void* d_ws, size_t ws_size,
                              hipStream_t stream) {
    const float* x = (const float*)d_in[0];
    float* out = (float*)d_out;
    char* w = (char*)d_ws;
    unsigned* minenc           = (unsigned*)(w + 1024);
    unsigned* maxenc           = (unsigned*)(w + 1280);
    unsigned long long* rmaxenc= (unsigned long long*)(w + 1536);
    double*  gsd               = (double*)(w + 256);
    float*   gw                = (float*)(w + 2048);                 // 6*288 floats (ends 8960)
    unsigned* rowact           = (unsigned*)(w + 9216);              // 48*16 words (ends 12288)
    float*   lap               = (float*)(w + 16384);                // 50331648 B
    double*  Rb                = (double*)(w + 16384 + 50331648);    // 100663296 B
    float*   T                 = (float*)Rb;                         // reused after maskTK
    unsigned char* maskb       = (unsigned char*)(w + 16384 + 50331648 + 100663296); // 12582912 B

    initK<<<1, 1024, 0, stream>>>(minenc, maxenc, rmaxenc, rowact);
    gaussK<<<6, 512, 0, stream>>>(gw);
    minmaxK<<<dim3(8, 48), 256, 0, stream>>>((const float4*)x, minenc, maxenc);
    scaleK<<<1, 64, 0, stream>>>(minenc, maxenc, gsd);
    lapRK<<<dim3(16, 16, 48), 256, 0, stream>>>(x, gsd, lap, Rb, rmaxenc);
    maskTK<<<dim3(16, 16, 48), 256, 0, stream>>>(Rb, rmaxenc, maskb, rowact);

    const int rr[6] = {4, 8, 17, 34, 67, 134};
    for (int o = 0; o < 6; ++o) {
        int r = rr[o];
        int nc16 = (2*r + 1 + 15) / 16;
        int nc8  = (2*r + 1 + 7) / 8;
        float sigma = 1.4f * (float)(1 << o);
        rowblurK<<<dim3(64, 48), 256, 0, stream>>>(lap, T, gw + o*288, r, nc16, rowact);
        int rowsAlloc = 256 + 8*nc8 + 8;
        size_t lds = (size_t)(rowsAlloc*36 + 288) * 4;
        colblurK<<<dim3(16, 2, 16), 256, lds, stream>>>(T, maskb, out, gw + o*288, r, nc8, rowsAlloc, sigma, o == 0 ? 1 : 0);
    }
}